// Round 1
// baseline (154.756 us; speedup 1.0000x reference)
//
#include <hip/hip_runtime.h>
#include <hip/hip_bf16.h>
#include <cstdint>

typedef __attribute__((ext_vector_type(8))) short bf16x8;
typedef __attribute__((ext_vector_type(4))) float f32x4;

#define T_SEQ 2048
#define NB    8
#define CDIM  1024
#define HDIM  128

__device__ __forceinline__ short f2bf(float f) {
  unsigned u = __float_as_uint(f);
  u += 0x7fff + ((u >> 16) & 1);   // RNE
  return (short)(u >> 16);
}

__device__ __forceinline__ unsigned pk2(float a, float b) {
  return (unsigned)(unsigned short)f2bf(a) | ((unsigned)(unsigned short)f2bf(b) << 16);
}

__device__ __forceinline__ void gload_lds16(const void* gsrc, void* lds_base_uniform) {
  __builtin_amdgcn_global_load_lds(
      (const __attribute__((address_space(1))) unsigned int*)gsrc,
      (__attribute__((address_space(3))) unsigned int*)lds_base_uniform,
      16, 0, 0);
}

// ---------------- bias table: bias[d] = log(sum_g alpha_g * g^d + 1e-8) ----------------
__global__ void msta_bias_kernel(const float* gfl, const float* gml, const float* gsl,
                                 const float* al, float* tab) {
  int d = blockIdx.x * 256 + threadIdx.x;
  if (d >= T_SEQ) return;
  float gf = 0.30f / (1.f + __expf(-gfl[0])) + 0.60f;
  float gm = 0.15f / (1.f + __expf(-gml[0])) + 0.85f;
  float gs = 0.05f / (1.f + __expf(-gsl[0])) + 0.95f;
  float a0 = al[0], a1 = al[1], a2 = al[2];
  float mx = fmaxf(a0, fmaxf(a1, a2));
  float e0 = __expf(a0 - mx), e1 = __expf(a1 - mx), e2 = __expf(a2 - mx);
  float inv = 1.f / (e0 + e1 + e2);
  float fd = (float)d;
  float mix = e0 * inv * __expf(fd * __logf(gf))
            + e1 * inv * __expf(fd * __logf(gm))
            + e2 * inv * __expf(fd * __logf(gs));
  tab[d] = __logf(mix + 1e-8f);
}

// ---------------- W transpose + bf16 cast; Wq gets the 1/sqrt(H) scale folded in -------
__global__ void msta_wt_kernel(const float* Wq, const float* Wk, const float* Wv, short* wt) {
  int idx = blockIdx.x * 256 + threadIdx.x;      // [0, 3*128*1024)
  int m = idx >> 17;
  int r = idx & 131071;
  int n = r >> 10;
  int kk = r & 1023;
  const float* W = (m == 0) ? Wq : ((m == 1) ? Wk : Wv);
  float v = W[kk * HDIM + n];
  if (m == 0) v *= 0.08838834764831845f;         // H^-0.5
  wt[idx] = f2bf(v);
}

// ---------------- QKV projection: 64 rows/block, 4 waves (2x2), bf16 MFMA --------------
__global__ __launch_bounds__(256) void msta_qkv_kernel(
    const float* __restrict__ x, const short* __restrict__ wt,
    short* __restrict__ q, short* __restrict__ k, short* __restrict__ vt) {
  __shared__ short xs[64 * 64];        // [row][k] swizzled, 8 KB
  __shared__ short wsm[3 * 128 * 64];  // [m][n][k] swizzled, 48 KB

  const int tid  = threadIdx.x;
  const int lane = tid & 63;
  const int w    = tid >> 6;
  const int rh   = w >> 1, ch = w & 1;
  const int lo   = lane & 15, hi = lane >> 4;
  const int r0   = blockIdx.x * 64;

  f32x4 acc[3][2][4];
  #pragma unroll
  for (int m = 0; m < 3; m++)
    #pragma unroll
    for (int f = 0; f < 2; f++)
      #pragma unroll
      for (int jf = 0; jf < 4; jf++)
        acc[m][f][jf] = (f32x4){0.f, 0.f, 0.f, 0.f};

  for (int k0 = 0; k0 < CDIM; k0 += 64) {
    // stage x tile (64x64 f32 -> bf16, swizzled write)
    {
      int row = tid >> 2, kc = tid & 3;
      const float4* s4 = (const float4*)(x + (size_t)(r0 + row) * CDIM + k0 + kc * 16);
      float4 f0 = s4[0], f1 = s4[1], f2 = s4[2], f3 = s4[3];
      uint4 lo_v, hi_v;
      lo_v.x = pk2(f0.x, f0.y); lo_v.y = pk2(f0.z, f0.w);
      lo_v.z = pk2(f1.x, f1.y); lo_v.w = pk2(f1.z, f1.w);
      hi_v.x = pk2(f2.x, f2.y); hi_v.y = pk2(f2.z, f2.w);
      hi_v.z = pk2(f3.x, f3.y); hi_v.w = pk2(f3.z, f3.w);
      int rb = row * 128, sw = (row & 7) << 4;
      *(uint4*)((char*)xs + rb + ((kc * 32) ^ sw))      = lo_v;
      *(uint4*)((char*)xs + rb + ((kc * 32 + 16) ^ sw)) = hi_v;
    }
    // stage 3 Wt tiles via global_load_lds (pre-swizzled source, linear LDS dest)
    #pragma unroll
    for (int m = 0; m < 3; m++) {
      #pragma unroll
      for (int i = 0; i < 4; i++) {
        int G = (w * 4 + i) * 64 + lane;           // granule id in [0,1024)
        int rr = G >> 3, g = G & 7;
        int c = g ^ (rr & 7);
        gload_lds16(wt + m * 131072 + rr * CDIM + k0 + c * 8,
                    (char*)wsm + m * 16384 + (w * 4 + i) * 1024);
      }
    }
    __syncthreads();

    #pragma unroll
    for (int kk = 0; kk < 2; kk++) {
      bf16x8 A[2];
      #pragma unroll
      for (int f = 0; f < 2; f++) {
        int row = rh * 32 + f * 16 + lo;
        int byteoff = row * 128 + (((kk * 64 + hi * 16)) ^ ((row & 7) << 4));
        A[f] = *(const bf16x8*)((const char*)xs + byteoff);
      }
      #pragma unroll
      for (int m = 0; m < 3; m++) {
        #pragma unroll
        for (int jf = 0; jf < 4; jf++) {
          int n = ch * 64 + jf * 16 + lo;
          int byteoff = m * 16384 + n * 128 + (((kk * 64 + hi * 16)) ^ ((n & 7) << 4));
          bf16x8 Bv = *(const bf16x8*)((const char*)wsm + byteoff);
          acc[m][0][jf] = __builtin_amdgcn_mfma_f32_16x16x32_bf16(A[0], Bv, acc[m][0][jf], 0, 0, 0);
          acc[m][1][jf] = __builtin_amdgcn_mfma_f32_16x16x32_bf16(A[1], Bv, acc[m][1][jf], 0, 0, 0);
        }
      }
    }
    __syncthreads();
  }

  // epilogue: q,k row-major bf16 [b*t][h]; v transposed [b][h][t]
  #pragma unroll
  for (int m = 0; m < 3; m++) {
    #pragma unroll
    for (int f = 0; f < 2; f++) {
      #pragma unroll
      for (int jf = 0; jf < 4; jf++) {
        f32x4 a = acc[m][f][jf];
        int col = ch * 64 + jf * 16 + lo;
        int rbase = r0 + rh * 32 + f * 16 + hi * 4;
        #pragma unroll
        for (int rg = 0; rg < 4; rg++) {
          int t = rbase + rg;
          short hv = f2bf(a[rg]);
          if (m == 0)      q[t * HDIM + col] = hv;
          else if (m == 1) k[t * HDIM + col] = hv;
          else {
            int b = t >> 11, tt = t & 2047;
            vt[((size_t)b * HDIM + col) * T_SEQ + tt] = hv;
          }
        }
      }
    }
  }
}

// ---------------- flash attention: QT=32 (2 waves), KT=64, online softmax --------------
__global__ __launch_bounds__(128) void msta_attn_kernel(
    const short* __restrict__ q, const short* __restrict__ kg,
    const short* __restrict__ vt, const float* __restrict__ bias_tab,
    float* __restrict__ out) {
  __shared__ short Ks[64 * 128];     // [s][h] swizzled, 16 KB
  __shared__ short Vs[128 * 64];     // [h][s] swizzled, 16 KB
  __shared__ short Ps[2][16 * 64];   // per-wave P, swizzled, 4 KB

  const int tid  = threadIdx.x;
  const int lane = tid & 63;
  const int wv   = tid >> 6;
  const int lo   = lane & 15, hi = lane >> 4;
  const int b    = blockIdx.x & 7;
  const int qt   = 63 - (blockIdx.x >> 3);   // LPT: longest q-tiles dispatched first
  const int q0   = qt * 32;

  // Q fragments in registers (16 rows per wave; Wq carried the 1/sqrt(H) scale)
  bf16x8 qf[4];
  const short* qbase = q + ((size_t)b * T_SEQ + q0 + wv * 16 + lo) * HDIM;
  #pragma unroll
  for (int ks = 0; ks < 4; ks++)
    qf[ks] = *(const bf16x8*)(qbase + ks * 32 + hi * 8);

  f32x4 oacc[8];
  #pragma unroll
  for (int jo = 0; jo < 8; jo++) oacc[jo] = (f32x4){0.f, 0.f, 0.f, 0.f};
  float mrow[4], lrow[4];
  #pragma unroll
  for (int rg = 0; rg < 4; rg++) { mrow[rg] = -1e30f; lrow[rg] = 0.f; }

  const int ntiles = qt / 2 + 1;
  const short* kb = kg + (size_t)b * T_SEQ * HDIM;
  const short* vb = vt + (size_t)b * HDIM * T_SEQ;

  for (int s0 = 0; s0 < ntiles * 64; s0 += 64) {
    // stage K tile [64][128] (16 granules/row) and Vt tile [128][64] (8 granules/row)
    #pragma unroll
    for (int i = 0; i < 8; i++) {
      int G = (wv * 8 + i) * 64 + lane;
      int r = G >> 4, g = G & 15;
      int c = g ^ (r & 7);
      gload_lds16(kb + (size_t)(s0 + r) * HDIM + c * 8, (char*)Ks + (wv * 8 + i) * 1024);
    }
    #pragma unroll
    for (int i = 0; i < 8; i++) {
      int G = (wv * 8 + i) * 64 + lane;
      int r = G >> 3, g = G & 7;
      int c = g ^ (r & 7);
      gload_lds16(vb + (size_t)r * T_SEQ + s0 + c * 8, (char*)Vs + (wv * 8 + i) * 1024);
    }
    __syncthreads();

    // S = Q @ K^T   (16 x 64 per wave)
    f32x4 sacc[4];
    #pragma unroll
    for (int jf = 0; jf < 4; jf++) sacc[jf] = (f32x4){0.f, 0.f, 0.f, 0.f};
    #pragma unroll
    for (int ks = 0; ks < 4; ks++) {
      #pragma unroll
      for (int jf = 0; jf < 4; jf++) {
        int s = jf * 16 + lo;
        int byteoff = s * 256 + (((ks * 64 + hi * 16)) ^ ((s & 7) << 4));
        bf16x8 kf = *(const bf16x8*)((const char*)Ks + byteoff);
        sacc[jf] = __builtin_amdgcn_mfma_f32_16x16x32_bf16(qf[ks], kf, sacc[jf], 0, 0, 0);
      }
    }

    // bias + causal mask
    float sv[4][4];
    #pragma unroll
    for (int jf = 0; jf < 4; jf++) {
      #pragma unroll
      for (int rg = 0; rg < 4; rg++) {
        int i_ = q0 + wv * 16 + hi * 4 + rg;
        int j_ = s0 + jf * 16 + lo;
        int d = i_ - j_;
        sv[jf][rg] = (d >= 0) ? (sacc[jf][rg] + bias_tab[d]) : -1e30f;
      }
    }

    // online softmax: row max (4 rows per 16-lane group), rescale O and l
    float mnew[4];
    #pragma unroll
    for (int rg = 0; rg < 4; rg++) {
      float mx = fmaxf(fmaxf(sv[0][rg], sv[1][rg]), fmaxf(sv[2][rg], sv[3][rg]));
      mx = fmaxf(mx, __shfl_xor(mx, 1));
      mx = fmaxf(mx, __shfl_xor(mx, 2));
      mx = fmaxf(mx, __shfl_xor(mx, 4));
      mx = fmaxf(mx, __shfl_xor(mx, 8));
      mnew[rg] = fmaxf(mrow[rg], mx);
      float sc = __expf(mrow[rg] - mnew[rg]);
      mrow[rg] = mnew[rg];
      lrow[rg] *= sc;
      #pragma unroll
      for (int jo = 0; jo < 8; jo++) oacc[jo][rg] *= sc;
    }

    // P = exp(sv - mnew) -> bf16 into per-wave LDS (A-layout bounce) + row sums
    float psum[4] = {0.f, 0.f, 0.f, 0.f};
    #pragma unroll
    for (int jf = 0; jf < 4; jf++) {
      #pragma unroll
      for (int rg = 0; rg < 4; rg++) {
        float p = __expf(sv[jf][rg] - mnew[rg]);
        psum[rg] += p;
        int prow = hi * 4 + rg;
        int pcol = jf * 16 + lo;
        int byteoff = prow * 128 + (((pcol * 2)) ^ ((prow & 7) << 4));
        *(short*)((char*)Ps[wv] + byteoff) = f2bf(p);
      }
    }
    #pragma unroll
    for (int rg = 0; rg < 4; rg++) {
      float s = psum[rg];
      s += __shfl_xor(s, 1); s += __shfl_xor(s, 2);
      s += __shfl_xor(s, 4); s += __shfl_xor(s, 8);
      lrow[rg] += s;
    }

    // O += P @ V
    #pragma unroll
    for (int ks = 0; ks < 2; ks++) {
      int prow = lo;
      int pbyte = prow * 128 + (((ks * 64 + hi * 16)) ^ ((prow & 7) << 4));
      bf16x8 pf = *(const bf16x8*)((const char*)Ps[wv] + pbyte);
      #pragma unroll
      for (int jo = 0; jo < 8; jo++) {
        int h = jo * 16 + lo;
        int vbyte = h * 128 + (((ks * 64 + hi * 16)) ^ ((h & 7) << 4));
        bf16x8 vf = *(const bf16x8*)((const char*)Vs + vbyte);
        oacc[jo] = __builtin_amdgcn_mfma_f32_16x16x32_bf16(pf, vf, oacc[jo], 0, 0, 0);
      }
    }
    __syncthreads();
  }

  // normalize + store fp32
  #pragma unroll
  for (int jo = 0; jo < 8; jo++) {
    #pragma unroll
    for (int rg = 0; rg < 4; rg++) {
      int t = q0 + wv * 16 + hi * 4 + rg;
      out[((size_t)b * T_SEQ + t) * HDIM + jo * 16 + lo] = oacc[jo][rg] / lrow[rg];
    }
  }
}

extern "C" void kernel_launch(void* const* d_in, const int* in_sizes, int n_in,
                              void* d_out, int out_size, void* d_ws, size_t ws_size,
                              hipStream_t stream) {
  (void)in_sizes; (void)n_in; (void)out_size; (void)ws_size;
  const float* x   = (const float*)d_in[0];
  const float* Wq  = (const float*)d_in[1];
  const float* Wk  = (const float*)d_in[2];
  const float* Wv  = (const float*)d_in[3];
  const float* gfl = (const float*)d_in[4];
  const float* gml = (const float*)d_in[5];
  const float* gsl = (const float*)d_in[6];
  const float* al  = (const float*)d_in[7];
  float* out = (float*)d_out;

  // ws layout: bias_tab f32[2048] @0 | q bf16 @8192 | k bf16 @8192+4M | vt bf16 @8192+8M
  //            | wt bf16[3][128][1024] @8192+12M   (total ~12.8 MB)
  char* wsb = (char*)d_ws;
  float* bias_tab = (float*)wsb;
  short* qw  = (short*)(wsb + 8192);
  short* kw  = (short*)(wsb + 8192 + 1 * 4194304);
  short* vtw = (short*)(wsb + 8192 + 2 * 4194304);
  short* wtw = (short*)(wsb + 8192 + 3 * 4194304);

  msta_bias_kernel<<<8, 256, 0, stream>>>(gfl, gml, gsl, al, bias_tab);
  msta_wt_kernel<<<1536, 256, 0, stream>>>(Wq, Wk, Wv, wtw);
  msta_qkv_kernel<<<256, 256, 0, stream>>>(x, wtw, qw, kw, vtw);
  msta_attn_kernel<<<512, 128, 0, stream>>>(qw, kw, vtw, bias_tab, out);
}

// Round 2
// 103.262 us; speedup vs baseline: 1.4987x; 1.4987x over previous
//
#include <hip/hip_runtime.h>
#include <hip/hip_bf16.h>
#include <cstdint>

typedef __attribute__((ext_vector_type(8))) short bf16x8;
typedef __attribute__((ext_vector_type(4))) float f32x4;

#define T_SEQ 2048
#define NB    8
#define CDIM  1024
#define HDIM  128
#define NQB   32      // q-blocks of 64 rows per batch

__device__ __forceinline__ short f2bf(float f) {
  unsigned u = __float_as_uint(f);
  u += 0x7fff + ((u >> 16) & 1);   // RNE
  return (short)(u >> 16);
}

__device__ __forceinline__ unsigned pk2(float a, float b) {
  return (unsigned)(unsigned short)f2bf(a) | ((unsigned)(unsigned short)f2bf(b) << 16);
}

__device__ __forceinline__ void gload_lds16(const void* gsrc, void* lds_base_uniform) {
  __builtin_amdgcn_global_load_lds(
      (const __attribute__((address_space(1))) unsigned int*)gsrc,
      (__attribute__((address_space(3))) unsigned int*)lds_base_uniform,
      16, 0, 0);
}

// ---------------- bias table: bias[d] = log(sum_g alpha_g * g^d + 1e-8) ----------------
__global__ void msta_bias_kernel(const float* gfl, const float* gml, const float* gsl,
                                 const float* al, float* tab) {
  int d = blockIdx.x * 256 + threadIdx.x;
  if (d >= T_SEQ) return;
  float gf = 0.30f / (1.f + __expf(-gfl[0])) + 0.60f;
  float gm = 0.15f / (1.f + __expf(-gml[0])) + 0.85f;
  float gs = 0.05f / (1.f + __expf(-gsl[0])) + 0.95f;
  float a0 = al[0], a1 = al[1], a2 = al[2];
  float mx = fmaxf(a0, fmaxf(a1, a2));
  float e0 = __expf(a0 - mx), e1 = __expf(a1 - mx), e2 = __expf(a2 - mx);
  float inv = 1.f / (e0 + e1 + e2);
  float fd = (float)d;
  float mix = e0 * inv * __expf(fd * __logf(gf))
            + e1 * inv * __expf(fd * __logf(gm))
            + e2 * inv * __expf(fd * __logf(gs));
  tab[d] = __logf(mix + 1e-8f);
}

// ---------------- W transpose + bf16 cast; Wq gets the 1/sqrt(H) scale folded in -------
__global__ void msta_wt_kernel(const float* Wq, const float* Wk, const float* Wv, short* wt) {
  int idx = blockIdx.x * 256 + threadIdx.x;      // [0, 3*128*1024)
  int m = idx >> 17;
  int r = idx & 131071;
  int n = r >> 10;
  int kk = r & 1023;
  const float* W = (m == 0) ? Wq : ((m == 1) ? Wk : Wv);
  float v = W[kk * HDIM + n];
  if (m == 0) v *= 0.08838834764831845f;         // H^-0.5
  wt[idx] = f2bf(v);
}

// ---------------- QKV projection: 64 rows/block, 4 waves (2x2), bf16 MFMA --------------
__global__ __launch_bounds__(256) void msta_qkv_kernel(
    const float* __restrict__ x, const short* __restrict__ wt,
    short* __restrict__ q, short* __restrict__ k, short* __restrict__ vt) {
  __shared__ short xs[64 * 64];        // [row][k] swizzled, 8 KB
  __shared__ short wsm[3 * 128 * 64];  // [m][n][k] swizzled, 48 KB

  const int tid  = threadIdx.x;
  const int lane = tid & 63;
  const int w    = tid >> 6;
  const int rh   = w >> 1, ch = w & 1;
  const int lo   = lane & 15, hi = lane >> 4;
  const int r0   = blockIdx.x * 64;

  f32x4 acc[3][2][4];
  #pragma unroll
  for (int m = 0; m < 3; m++)
    #pragma unroll
    for (int f = 0; f < 2; f++)
      #pragma unroll
      for (int jf = 0; jf < 4; jf++)
        acc[m][f][jf] = (f32x4){0.f, 0.f, 0.f, 0.f};

  for (int k0 = 0; k0 < CDIM; k0 += 64) {
    // stage x tile (64x64 f32 -> bf16, swizzled write)
    {
      int row = tid >> 2, kc = tid & 3;
      const float4* s4 = (const float4*)(x + (size_t)(r0 + row) * CDIM + k0 + kc * 16);
      float4 f0 = s4[0], f1 = s4[1], f2 = s4[2], f3 = s4[3];
      uint4 lo_v, hi_v;
      lo_v.x = pk2(f0.x, f0.y); lo_v.y = pk2(f0.z, f0.w);
      lo_v.z = pk2(f1.x, f1.y); lo_v.w = pk2(f1.z, f1.w);
      hi_v.x = pk2(f2.x, f2.y); hi_v.y = pk2(f2.z, f2.w);
      hi_v.z = pk2(f3.x, f3.y); hi_v.w = pk2(f3.z, f3.w);
      int rb = row * 128, sw = (row & 7) << 4;
      *(uint4*)((char*)xs + rb + ((kc * 32) ^ sw))      = lo_v;
      *(uint4*)((char*)xs + rb + ((kc * 32 + 16) ^ sw)) = hi_v;
    }
    // stage 3 Wt tiles via global_load_lds (pre-swizzled source, linear LDS dest)
    #pragma unroll
    for (int m = 0; m < 3; m++) {
      #pragma unroll
      for (int i = 0; i < 4; i++) {
        int G = (w * 4 + i) * 64 + lane;           // granule id in [0,1024)
        int rr = G >> 3, g = G & 7;
        int c = g ^ (rr & 7);
        gload_lds16(wt + m * 131072 + rr * CDIM + k0 + c * 8,
                    (char*)wsm + m * 16384 + (w * 4 + i) * 1024);
      }
    }
    __syncthreads();

    #pragma unroll
    for (int kk = 0; kk < 2; kk++) {
      bf16x8 A[2];
      #pragma unroll
      for (int f = 0; f < 2; f++) {
        int row = rh * 32 + f * 16 + lo;
        int byteoff = row * 128 + (((kk * 64 + hi * 16)) ^ ((row & 7) << 4));
        A[f] = *(const bf16x8*)((const char*)xs + byteoff);
      }
      #pragma unroll
      for (int m = 0; m < 3; m++) {
        #pragma unroll
        for (int jf = 0; jf < 4; jf++) {
          int n = ch * 64 + jf * 16 + lo;
          int byteoff = m * 16384 + n * 128 + (((kk * 64 + hi * 16)) ^ ((n & 7) << 4));
          bf16x8 Bv = *(const bf16x8*)((const char*)wsm + byteoff);
          acc[m][0][jf] = __builtin_amdgcn_mfma_f32_16x16x32_bf16(A[0], Bv, acc[m][0][jf], 0, 0, 0);
          acc[m][1][jf] = __builtin_amdgcn_mfma_f32_16x16x32_bf16(A[1], Bv, acc[m][1][jf], 0, 0, 0);
        }
      }
    }
    __syncthreads();
  }

  // epilogue: q,k row-major bf16 [b*t][h]; v transposed [b][h][t]
  #pragma unroll
  for (int m = 0; m < 3; m++) {
    #pragma unroll
    for (int f = 0; f < 2; f++) {
      #pragma unroll
      for (int jf = 0; jf < 4; jf++) {
        f32x4 a = acc[m][f][jf];
        int col = ch * 64 + jf * 16 + lo;
        int rbase = r0 + rh * 32 + f * 16 + hi * 4;
        #pragma unroll
        for (int rg = 0; rg < 4; rg++) {
          int t = rbase + rg;
          short hv = f2bf(a[rg]);
          if (m == 0)      q[t * HDIM + col] = hv;
          else if (m == 1) k[t * HDIM + col] = hv;
          else {
            int b = t >> 11, tt = t & 2047;
            vt[((size_t)b * HDIM + col) * T_SEQ + tt] = hv;
          }
        }
      }
    }
  }
}

// ---------------- flash attention: 4 waves (64 q-rows), KT=64, dbuf, S-split -----------
template <int SP>
__global__ __launch_bounds__(256) void msta_attn_kernel(
    const short* __restrict__ q, const short* __restrict__ kg,
    const short* __restrict__ vt, const float* __restrict__ bias_tab,
    float* __restrict__ out, float* __restrict__ opart, float2* __restrict__ ml) {
  __shared__ short Ks[2][64 * 128];   // [buf][s][h] swizzled, 2x16 KB
  __shared__ short Vs[2][128 * 64];   // [buf][h][s] swizzled, 2x16 KB
  __shared__ short Ps[4][16 * 64];    // per-wave P, swizzled, 8 KB

  const int tid  = threadIdx.x;
  const int lane = tid & 63;
  const int w    = tid >> 6;
  const int lo   = lane & 15, hi = lane >> 4;

  const int idx = blockIdx.x;
  const int qb  = (NQB - 1) - idx / (NB * SP);   // LPT: longest q-blocks first
  const int rem = idx % (NB * SP);
  const int b   = rem / SP;
  const int sp  = rem % SP;
  const int q0  = qb * 64;

  const int nt  = qb + 1;                        // causal tile count for this q-block
  const int csz = (nt + SP - 1) / SP;
  const int t0  = sp * csz;
  const int t1  = (t0 + csz < nt) ? (t0 + csz) : nt;

  if (t0 >= t1) {                                // empty chunk: flag l=0 and exit
    if (SP > 1 && lane < 16) {
      int t = q0 + w * 16 + lane;
      ml[((size_t)sp * NB + b) * T_SEQ + t] = make_float2(-1e30f, 0.f);
    }
    return;
  }

  const short* kb = kg + (size_t)b * T_SEQ * HDIM;
  const short* vb = vt + (size_t)b * HDIM * T_SEQ;

  // Q fragments in registers (16 rows per wave; Wq carried the 1/sqrt(H) scale)
  bf16x8 qf[4];
  const short* qbase = q + ((size_t)b * T_SEQ + q0 + w * 16 + lo) * HDIM;
  #pragma unroll
  for (int ks = 0; ks < 4; ks++)
    qf[ks] = *(const bf16x8*)(qbase + ks * 32 + hi * 8);

  f32x4 oacc[8];
  #pragma unroll
  for (int jo = 0; jo < 8; jo++) oacc[jo] = (f32x4){0.f, 0.f, 0.f, 0.f};
  float mrow[4], lrow[4];
  #pragma unroll
  for (int rg = 0; rg < 4; rg++) { mrow[rg] = -1e30f; lrow[rg] = 0.f; }

  auto stage = [&](int t, int buf) {
    int s0 = t * 64;
    #pragma unroll
    for (int i = 0; i < 4; i++) {                // K: 1024 granules, 4/thread
      int slot = w * 4 + i;
      int G = slot * 64 + lane;
      int r = G >> 4;
      int c = (lane & 15) ^ (r & 7);
      gload_lds16(kb + (size_t)(s0 + r) * HDIM + c * 8, (char*)Ks[buf] + slot * 1024);
    }
    #pragma unroll
    for (int i = 0; i < 4; i++) {                // Vt: 1024 granules, 4/thread
      int slot = w * 4 + i;
      int G = slot * 64 + lane;
      int r = G >> 3;
      int c = (G & 7) ^ (r & 7);
      gload_lds16(vb + (size_t)r * T_SEQ + s0 + c * 8, (char*)Vs[buf] + slot * 1024);
    }
  };

  stage(t0, 0);
  __syncthreads();

  int cur = 0;
  for (int t = t0; t < t1; ++t, cur ^= 1) {
    if (t + 1 < t1) stage(t + 1, cur ^ 1);       // prefetch next tile (hidden under compute)
    const int s0 = t * 64;

    // S = Q @ K^T   (16 x 64 per wave)
    f32x4 sacc[4];
    #pragma unroll
    for (int jf = 0; jf < 4; jf++) sacc[jf] = (f32x4){0.f, 0.f, 0.f, 0.f};
    #pragma unroll
    for (int ks = 0; ks < 4; ks++) {
      #pragma unroll
      for (int jf = 0; jf < 4; jf++) {
        int s = jf * 16 + lo;
        int byteoff = s * 256 + (((ks * 64 + hi * 16)) ^ ((s & 7) << 4));
        bf16x8 kf = *(const bf16x8*)((const char*)Ks[cur] + byteoff);
        sacc[jf] = __builtin_amdgcn_mfma_f32_16x16x32_bf16(qf[ks], kf, sacc[jf], 0, 0, 0);
      }
    }

    // bias + causal mask
    float sv[4][4];
    #pragma unroll
    for (int jf = 0; jf < 4; jf++) {
      #pragma unroll
      for (int rg = 0; rg < 4; rg++) {
        int i_ = q0 + w * 16 + hi * 4 + rg;
        int j_ = s0 + jf * 16 + lo;
        int d = i_ - j_;
        sv[jf][rg] = (d >= 0) ? (sacc[jf][rg] + bias_tab[d]) : -1e30f;
      }
    }

    // online softmax: row max (4 rows per 16-lane group), rescale O and l
    float mnew[4];
    #pragma unroll
    for (int rg = 0; rg < 4; rg++) {
      float mx = fmaxf(fmaxf(sv[0][rg], sv[1][rg]), fmaxf(sv[2][rg], sv[3][rg]));
      mx = fmaxf(mx, __shfl_xor(mx, 1));
      mx = fmaxf(mx, __shfl_xor(mx, 2));
      mx = fmaxf(mx, __shfl_xor(mx, 4));
      mx = fmaxf(mx, __shfl_xor(mx, 8));
      mnew[rg] = fmaxf(mrow[rg], mx);
      float sc = __expf(mrow[rg] - mnew[rg]);
      mrow[rg] = mnew[rg];
      lrow[rg] *= sc;
      #pragma unroll
      for (int jo = 0; jo < 8; jo++) oacc[jo][rg] *= sc;
    }

    // P = exp(sv - mnew) -> bf16 into per-wave LDS (A-layout bounce) + row sums
    float psum[4] = {0.f, 0.f, 0.f, 0.f};
    #pragma unroll
    for (int jf = 0; jf < 4; jf++) {
      #pragma unroll
      for (int rg = 0; rg < 4; rg++) {
        float p = __expf(sv[jf][rg] - mnew[rg]);
        psum[rg] += p;
        int prow = hi * 4 + rg;
        int pcol = jf * 16 + lo;
        int byteoff = prow * 128 + (((pcol * 2)) ^ ((prow & 7) << 4));
        *(short*)((char*)Ps[w] + byteoff) = f2bf(p);
      }
    }
    #pragma unroll
    for (int rg = 0; rg < 4; rg++) {
      float s = psum[rg];
      s += __shfl_xor(s, 1); s += __shfl_xor(s, 2);
      s += __shfl_xor(s, 4); s += __shfl_xor(s, 8);
      lrow[rg] += s;
    }

    // O += P @ V
    #pragma unroll
    for (int ks = 0; ks < 2; ks++) {
      int prow = lo;
      int pbyte = prow * 128 + (((ks * 64 + hi * 16)) ^ ((prow & 7) << 4));
      bf16x8 pf = *(const bf16x8*)((const char*)Ps[w] + pbyte);
      #pragma unroll
      for (int jo = 0; jo < 8; jo++) {
        int h = jo * 16 + lo;
        int vbyte = h * 128 + (((ks * 64 + hi * 16)) ^ ((h & 7) << 4));
        bf16x8 vf = *(const bf16x8*)((const char*)Vs[cur] + vbyte);
        oacc[jo] = __builtin_amdgcn_mfma_f32_16x16x32_bf16(pf, vf, oacc[jo], 0, 0, 0);
      }
    }
    __syncthreads();   // drains prefetch vmcnt; releases buf for next overwrite
  }

  if constexpr (SP == 1) {
    // normalize + store fp32
    #pragma unroll
    for (int jo = 0; jo < 8; jo++) {
      #pragma unroll
      for (int rg = 0; rg < 4; rg++) {
        int t = q0 + w * 16 + hi * 4 + rg;
        out[((size_t)b * T_SEQ + t) * HDIM + jo * 16 + lo] = oacc[jo][rg] / lrow[rg];
      }
    }
  } else {
    // unnormalized partial O + (m,l)
    #pragma unroll
    for (int jo = 0; jo < 8; jo++) {
      #pragma unroll
      for (int rg = 0; rg < 4; rg++) {
        int t = q0 + w * 16 + hi * 4 + rg;
        opart[(((size_t)sp * NB + b) * T_SEQ + t) * HDIM + jo * 16 + lo] = oacc[jo][rg];
      }
    }
    if (lo == 0) {
      #pragma unroll
      for (int rg = 0; rg < 4; rg++) {
        int t = q0 + w * 16 + hi * 4 + rg;
        ml[((size_t)sp * NB + b) * T_SEQ + t] = make_float2(mrow[rg], lrow[rg]);
      }
    }
  }
}

// ---------------- merge of S-split partials --------------------------------------------
__global__ __launch_bounds__(256) void msta_merge_kernel(
    const float* __restrict__ opart, const float2* __restrict__ ml,
    float* __restrict__ out) {
  int id  = blockIdx.x * 256 + threadIdx.x;   // [0, NB*T_SEQ*32)
  int row = id >> 5;                          // b*T_SEQ + t
  int c4  = id & 31;

  float2 v[4];
  float m = -1e30f;
  #pragma unroll
  for (int sp = 0; sp < 4; sp++) {
    v[sp] = ml[(size_t)sp * (NB * T_SEQ) + row];
    if (v[sp].y > 0.f) m = fmaxf(m, v[sp].x);
  }
  float denom = 0.f;
  float wgt[4];
  #pragma unroll
  for (int sp = 0; sp < 4; sp++) {
    wgt[sp] = (v[sp].y > 0.f) ? __expf(v[sp].x - m) : 0.f;
    denom += wgt[sp] * v[sp].y;
  }
  float4 acc = {0.f, 0.f, 0.f, 0.f};
  #pragma unroll
  for (int sp = 0; sp < 4; sp++) {
    if (wgt[sp] != 0.f) {
      float4 o = *(const float4*)(opart + ((size_t)sp * (NB * T_SEQ) + row) * HDIM + c4 * 4);
      acc.x += wgt[sp] * o.x; acc.y += wgt[sp] * o.y;
      acc.z += wgt[sp] * o.z; acc.w += wgt[sp] * o.w;
    }
  }
  float inv = 1.f / denom;
  float4 r = make_float4(acc.x * inv, acc.y * inv, acc.z * inv, acc.w * inv);
  *(float4*)(out + (size_t)row * HDIM + c4 * 4) = r;
}

extern "C" void kernel_launch(void* const* d_in, const int* in_sizes, int n_in,
                              void* d_out, int out_size, void* d_ws, size_t ws_size,
                              hipStream_t stream) {
  (void)in_sizes; (void)n_in; (void)out_size;
  const float* x   = (const float*)d_in[0];
  const float* Wq  = (const float*)d_in[1];
  const float* Wk  = (const float*)d_in[2];
  const float* Wv  = (const float*)d_in[3];
  const float* gfl = (const float*)d_in[4];
  const float* gml = (const float*)d_in[5];
  const float* gsl = (const float*)d_in[6];
  const float* al  = (const float*)d_in[7];
  float* out = (float*)d_out;

  // ws layout (bytes):
  //   bias f32[2048]                @ 0
  //   q    bf16[8*2048*128]         @ 8192
  //   k    bf16                     @ 8192 + 4 MiB
  //   vt   bf16                     @ 8192 + 8 MiB
  //   wt   bf16[3*128*1024]         @ 8192 + 12 MiB   (768 KiB)
  //   opart f32[4][8*2048][128]     @ 13639680        (32 MiB)
  //   ml    float2[4][8*2048]       @ 47194112        (512 KiB)
  char* wsb = (char*)d_ws;
  float*  bias_tab = (float*)wsb;
  short*  qw   = (short*)(wsb + 8192);
  short*  kw   = (short*)(wsb + 8192 + 1 * 4194304);
  short*  vtw  = (short*)(wsb + 8192 + 2 * 4194304);
  short*  wtw  = (short*)(wsb + 8192 + 3 * 4194304);
  float*  opart = (float*)(wsb + 13639680);
  float2* mlp   = (float2*)(wsb + 47194112);
  const size_t need = 47194112 + 524288;

  msta_bias_kernel<<<8, 256, 0, stream>>>(gfl, gml, gsl, al, bias_tab);
  msta_wt_kernel<<<1536, 256, 0, stream>>>(Wq, Wk, Wv, wtw);
  msta_qkv_kernel<<<256, 256, 0, stream>>>(x, wtw, qw, kw, vtw);

  if (ws_size >= need) {
    msta_attn_kernel<4><<<NB * NQB * 4, 256, 0, stream>>>(qw, kw, vtw, bias_tab,
                                                          nullptr, opart, mlp);
    msta_merge_kernel<<<(NB * T_SEQ * 32) / 256, 256, 0, stream>>>(opart, mlp, out);
  } else {
    msta_attn_kernel<1><<<NB * NQB, 256, 0, stream>>>(qw, kw, vtw, bias_tab,
                                                      out, nullptr, nullptr);
  }
}